// Round 1
// baseline (153.657 us; speedup 1.0000x reference)
//
#include <hip/hip_runtime.h>

// Problem constants (from reference)
#define NITEMS 100000
#define NRATE  5
#define BB     4096
#define LL     200
#define DD     64

typedef short short8 __attribute__((ext_vector_type(8)));
typedef float f32x4  __attribute__((ext_vector_type(4)));

static __device__ __forceinline__ short f2bf(float f) {
  // round-to-nearest-even fp32 -> bf16 (finite inputs only)
  unsigned u = __builtin_bit_cast(unsigned, f);
  u += 0x7fffu + ((u >> 16) & 1u);
  return (short)(u >> 16);
}
static __device__ __forceinline__ float bf2f(short s) {
  return __builtin_bit_cast(float, (unsigned)((unsigned short)s) << 16);
}

// ---------------------------------------------------------------------------
// Kernel A: pre_uv[item][o] = sum_i v2e[item][i] * w1_W[o][i]   (bf16 out)
// MFMA 16x16x32_bf16: A = v2e rows (M=items), B = W1a^T (N=o), K=i (64 -> 2 steps)
// ---------------------------------------------------------------------------
__global__ __launch_bounds__(256) void k_pre_uv(
    const float* __restrict__ v2e, const float* __restrict__ w1W,
    short* __restrict__ pre_uv)
{
  const int tid  = threadIdx.x;
  const int wave = tid >> 6, lane = tid & 63;
  const int n = lane & 15, quad = lane >> 4;
  const int ibase = (blockIdx.x * 4 + wave) * 16;
  if (ibase >= NITEMS) return;

  // B fragment: B[k][n] = w1_W[n][k], k = kh*32 + quad*8 + j
  short8 bfr[2][4];
#pragma unroll
  for (int nt = 0; nt < 4; ++nt)
#pragma unroll
    for (int kh = 0; kh < 2; ++kh) {
      const float* p = w1W + (nt * 16 + n) * 128 + kh * 32 + quad * 8;
      short8 f;
#pragma unroll
      for (int j = 0; j < 8; ++j) f[j] = f2bf(p[j]);
      bfr[kh][nt] = f;
    }

  // A fragment: A[m=lane&15][k=quad*8+j]
  const int row = min(ibase + n, NITEMS - 1);
  short8 afr[2];
#pragma unroll
  for (int kh = 0; kh < 2; ++kh) {
    const float* p = v2e + row * 64 + kh * 32 + quad * 8;
    short8 a;
#pragma unroll
    for (int j = 0; j < 8; ++j) a[j] = f2bf(p[j]);
    afr[kh] = a;
  }

  f32x4 d[4];
#pragma unroll
  for (int nt = 0; nt < 4; ++nt) {
    f32x4 z = {0.f, 0.f, 0.f, 0.f};
    z = __builtin_amdgcn_mfma_f32_16x16x32_bf16(afr[0], bfr[0][nt], z, 0, 0, 0);
    z = __builtin_amdgcn_mfma_f32_16x16x32_bf16(afr[1], bfr[1][nt], z, 0, 0, 0);
    d[nt] = z;
  }

  // C/D layout: col = lane&15 (o), row m = quad*4 + reg
#pragma unroll
  for (int nt = 0; nt < 4; ++nt)
#pragma unroll
    for (int r = 0; r < 4; ++r) {
      const int item = ibase + quad * 4 + r;
      if (item < NITEMS) pre_uv[item * 64 + nt * 16 + n] = f2bf(d[nt][r]);
    }
}

// ---------------------------------------------------------------------------
// Kernel B (tiny): pre_r5[r][o] = sum_i r2e[r][i]*w1_W[o][64+i] + w1_b[o] (fp32)
//                  w2bf = bf16 copy of w2_W (row-major [o][i])
// ---------------------------------------------------------------------------
__global__ __launch_bounds__(384) void k_pre_small(
    const float* __restrict__ r2e, const float* __restrict__ w1W,
    const float* __restrict__ w1b, const float* __restrict__ w2W,
    float* __restrict__ pre_r5, short* __restrict__ w2bf)
{
  const int tid = threadIdx.x;
  if (tid < NRATE * 64) {
    const int r = tid >> 6, o = tid & 63;
    float s = w1b[o];
    for (int i = 0; i < 64; ++i) s += r2e[r * 64 + i] * w1W[o * 128 + 64 + i];
    pre_r5[r * 64 + o] = s;
  }
  for (int idx = tid; idx < 64 * 64; idx += 384) w2bf[idx] = f2bf(w2W[idx]);
}

// ---------------------------------------------------------------------------
// Main kernel: one block per b. h = relu(pre_uv[uv]+pre_r5[r]) -> bf16,
// layer 2 via MFMA, relu+bias per row, running sum over l, mean at the end.
// ---------------------------------------------------------------------------
__global__ __launch_bounds__(256) void k_main(
    const short* __restrict__ pre_uv, const float* __restrict__ pre_r5,
    const short* __restrict__ w2bf, const float* __restrict__ w2b,
    const int* __restrict__ huv, const int* __restrict__ hrr,
    float* __restrict__ out)
{
  const int tid  = threadIdx.x;
  const int wave = tid >> 6, lane = tid & 63;
  const int n = lane & 15, quad = lane >> 4;
  const int b = blockIdx.x;

  // B fragments for W2^T: B[k][n] = w2[n][k]
  short8 bfr[2][4];
#pragma unroll
  for (int nt = 0; nt < 4; ++nt)
#pragma unroll
    for (int kh = 0; kh < 2; ++kh)
      bfr[kh][nt] = *reinterpret_cast<const short8*>(
          w2bf + (nt * 16 + n) * 64 + kh * 32 + quad * 8);

  float bias[4];
#pragma unroll
  for (int nt = 0; nt < 4; ++nt) bias[nt] = w2b[nt * 16 + n];

  float acc[4] = {0.f, 0.f, 0.f, 0.f};
  const int* hu = huv + b * LL;
  const int* hr = hrr + b * LL;

  // wave w handles l-tiles starting at w*16, stride 64 -> 13 tiles total
  for (int lbase = wave * 16; lbase < LL; lbase += 64) {
    const int l  = lbase + n;
    const int lc = l < LL ? l : LL - 1;   // clamp; masked in epilogue
    const int iv = hu[lc];
    const int ir = hr[lc];

    short8 afr[2];
#pragma unroll
    for (int kh = 0; kh < 2; ++kh) {
      short8 u = *reinterpret_cast<const short8*>(
          pre_uv + iv * 64 + kh * 32 + quad * 8);
      const float4* pr = reinterpret_cast<const float4*>(
          pre_r5 + ir * 64 + kh * 32 + quad * 8);
      const float4 r0 = pr[0], r1 = pr[1];
      const float rv[8] = {r0.x, r0.y, r0.z, r0.w, r1.x, r1.y, r1.z, r1.w};
      short8 a;
#pragma unroll
      for (int j = 0; j < 8; ++j) {
        const float h = bf2f(u[j]) + rv[j];
        a[j] = f2bf(fmaxf(h, 0.f));
      }
      afr[kh] = a;
    }

    f32x4 d[4];
#pragma unroll
    for (int nt = 0; nt < 4; ++nt) {
      f32x4 z = {0.f, 0.f, 0.f, 0.f};
      z = __builtin_amdgcn_mfma_f32_16x16x32_bf16(afr[0], bfr[0][nt], z, 0, 0, 0);
      z = __builtin_amdgcn_mfma_f32_16x16x32_bf16(afr[1], bfr[1][nt], z, 0, 0, 0);
      d[nt] = z;
    }

    // bias + relu per (row, o), mask padded rows, accumulate sum over rows/l
#pragma unroll
    for (int nt = 0; nt < 4; ++nt) {
#pragma unroll
      for (int r = 0; r < 4; ++r) {
        const int rl = lbase + quad * 4 + r;
        const float v = fmaxf(d[nt][r] + bias[nt], 0.f);
        acc[nt] += (rl < LL) ? v : 0.f;
      }
    }
  }

  // sum across the 4 quads (rows are split across quads)
#pragma unroll
  for (int nt = 0; nt < 4; ++nt) {
    float v = acc[nt];
    v += __shfl_xor(v, 16, 64);
    v += __shfl_xor(v, 32, 64);
    acc[nt] = v;
  }

  __shared__ float red[4][64];
  if (lane < 16) {
#pragma unroll
    for (int nt = 0; nt < 4; ++nt) red[wave][nt * 16 + lane] = acc[nt];
  }
  __syncthreads();
  if (tid < 64) {
    const float s = red[0][tid] + red[1][tid] + red[2][tid] + red[3][tid];
    out[b * 64 + tid] = s * (1.0f / (float)LL);
  }
}

// ---------------------------------------------------------------------------
// Fallback (no workspace): all-fp32, one block per b, weights in padded LDS.
// Correct but slow (~hundreds of µs); only used if ws_size is too small.
// ---------------------------------------------------------------------------
__global__ __launch_bounds__(256) void k_fallback(
    const float* __restrict__ v2e, const float* __restrict__ r2e,
    const float* __restrict__ w1W, const float* __restrict__ w1b,
    const float* __restrict__ w2W, const float* __restrict__ w2b,
    const int* __restrict__ huv, const int* __restrict__ hrr,
    float* __restrict__ out)
{
  __shared__ float sw1[64][129];   // +1 pad breaks o-stride bank conflicts
  __shared__ float sw2[64][65];
  __shared__ float sx[4][128];
  __shared__ float sh[4][64];
  __shared__ float red[4][64];

  const int tid = threadIdx.x;
  const int wave = tid >> 6, lane = tid & 63;
  const int b = blockIdx.x;

  for (int idx = tid; idx < 64 * 128; idx += 256) sw1[idx >> 7][idx & 127] = w1W[idx];
  for (int idx = tid; idx < 64 * 64; idx += 256) sw2[idx >> 6][idx & 63] = w2W[idx];
  __syncthreads();

  const float b1o = w1b[lane], b2o = w2b[lane];
  float acc = 0.f;

  for (int l = wave; l < LL; l += 4) {   // 200/4 = 50, uniform trip count
    const int iv = huv[b * LL + l];
    const int ir = hrr[b * LL + l];
    sx[wave][lane]      = v2e[iv * 64 + lane];
    sx[wave][64 + lane] = r2e[ir * 64 + lane];
    __syncthreads();
    float h = b1o;
    for (int i = 0; i < 128; ++i) h += sx[wave][i] * sw1[lane][i];
    sh[wave][lane] = fmaxf(h, 0.f);
    __syncthreads();
    float o = b2o;
    for (int i = 0; i < 64; ++i) o += sh[wave][i] * sw2[lane][i];
    acc += fmaxf(o, 0.f);
  }

  red[wave][lane] = acc;
  __syncthreads();
  if (tid < 64) {
    const float s = red[0][tid] + red[1][tid] + red[2][tid] + red[3][tid];
    out[b * 64 + tid] = s * (1.0f / (float)LL);
  }
}

extern "C" void kernel_launch(void* const* d_in, const int* in_sizes, int n_in,
                              void* d_out, int out_size, void* d_ws, size_t ws_size,
                              hipStream_t stream) {
  (void)in_sizes; (void)n_in; (void)out_size;
  const float* v2e = (const float*)d_in[0];   // [100000,64]
  const float* r2e = (const float*)d_in[1];   // [5,64]
  const float* w1W = (const float*)d_in[2];   // [64,128]
  const float* w1b = (const float*)d_in[3];   // [64]
  const float* w2W = (const float*)d_in[4];   // [64,64]
  const float* w2b = (const float*)d_in[5];   // [64]
  // d_in[6] = nodes (unused by uv=True branch)
  const int* huv = (const int*)d_in[7];       // [4096,200]
  const int* hrr = (const int*)d_in[8];       // [4096,200]
  float* out = (float*)d_out;                 // [4096,64]

  const size_t OFF_R5 = (size_t)NITEMS * 64 * sizeof(short);   // 12,800,000
  const size_t OFF_W2 = OFF_R5 + NRATE * 64 * sizeof(float);   // +1,280
  const size_t NEED   = OFF_W2 + 64 * 64 * sizeof(short);      // +8,192

  if (ws_size >= NEED) {
    short* pre_uv = (short*)d_ws;
    float* pre_r5 = (float*)((char*)d_ws + OFF_R5);
    short* w2bf   = (short*)((char*)d_ws + OFF_W2);

    k_pre_small<<<1, 384, 0, stream>>>(r2e, w1W, w1b, w2W, pre_r5, w2bf);
    k_pre_uv<<<(NITEMS + 63) / 64, 256, 0, stream>>>(v2e, w1W, pre_uv);
    k_main<<<BB, 256, 0, stream>>>(pre_uv, pre_r5, w2bf, w2b, huv, hrr, out);
  } else {
    k_fallback<<<BB, 256, 0, stream>>>(v2e, r2e, w1W, w1b, w2W, w2b, huv, hrr, out);
  }
}

// Round 2
// 128.516 us; speedup vs baseline: 1.1956x; 1.1956x over previous
//
#include <hip/hip_runtime.h>

// Problem constants (from reference)
#define NITEMS 100000
#define NRATE  5
#define BB     4096
#define LL     200
#define DD     64

typedef short short8 __attribute__((ext_vector_type(8)));
typedef short short4v __attribute__((ext_vector_type(4)));
typedef float f32x4  __attribute__((ext_vector_type(4)));

static __device__ __forceinline__ short f2bf(float f) {
  // round-to-nearest-even fp32 -> bf16 (finite inputs only)
  unsigned u = __builtin_bit_cast(unsigned, f);
  u += 0x7fffu + ((u >> 16) & 1u);
  return (short)(u >> 16);
}
static __device__ __forceinline__ float bf2f(short s) {
  return __builtin_bit_cast(float, (unsigned)((unsigned short)s) << 16);
}

// ---------------------------------------------------------------------------
// k_prep: 13 blocks x 256.
//  blocks 0-3 : w1abf[o*64+k] = bf16(w1_W[o][k])      (k<64, item half)
//  blocks 4-7 : w2bf [o*64+k] = bf16(w2_W[o][k])
//  blocks 8-12: pre_r5[r][o]  = w1_b[o] + sum_i r2e[r][i]*w1_W[o][64+i] (fp32)
// ---------------------------------------------------------------------------
__global__ __launch_bounds__(256) void k_prep(
    const float* __restrict__ r2e, const float* __restrict__ w1W,
    const float* __restrict__ w1b, const float* __restrict__ w2W,
    short* __restrict__ w1abf, short* __restrict__ w2bf,
    float* __restrict__ pre_r5)
{
  const int tid = threadIdx.x;
  const int blk = blockIdx.x;
  if (blk < 4) {
    const int g = blk * 256 + tid;      // 0..1023, 4 elems each of 4096
    const int base = g * 4;
    const int o = base >> 6, k = base & 63;
    const float4 v = *reinterpret_cast<const float4*>(w1W + o * 128 + k);
    short4v s = {f2bf(v.x), f2bf(v.y), f2bf(v.z), f2bf(v.w)};
    *reinterpret_cast<short4v*>(w1abf + base) = s;
  } else if (blk < 8) {
    const int g = (blk - 4) * 256 + tid;
    const int base = g * 4;
    const float4 v = *reinterpret_cast<const float4*>(w2W + base);
    short4v s = {f2bf(v.x), f2bf(v.y), f2bf(v.z), f2bf(v.w)};
    *reinterpret_cast<short4v*>(w2bf + base) = s;
  } else {
    const int r = blk - 8;
    if (tid < 64) {
      const int o = tid;
      const float4* wr = reinterpret_cast<const float4*>(w1W + o * 128 + 64);
      const float4* rr = reinterpret_cast<const float4*>(r2e + r * 64);
      float s = w1b[o];
#pragma unroll
      for (int q = 0; q < 16; ++q) {
        const float4 a = wr[q], b = rr[q];
        s += a.x * b.x + a.y * b.y + a.z * b.z + a.w * b.w;
      }
      pre_r5[r * 64 + o] = s;
    }
  }
}

// ---------------------------------------------------------------------------
// k_pre_uv: pre_uv[item][o] = bf16( sum_i v2e[item][i] * w1_W[o][i] )
// 64 items/block (16 per wave). B-frags from preconverted w1abf (b128 loads),
// A from float4 v2e loads, output transposed through LDS -> b128 stores.
// ---------------------------------------------------------------------------
__global__ __launch_bounds__(256) void k_pre_uv(
    const float* __restrict__ v2e, const short* __restrict__ w1abf,
    short* __restrict__ pre_uv)
{
  __shared__ __align__(16) short sD[4][16][72];  // 72: 16B-aligned rows, bank spread
  const int tid  = threadIdx.x;
  const int wave = tid >> 6, lane = tid & 63;
  const int n = lane & 15, quad = lane >> 4;
  const int ibase = blockIdx.x * 64 + wave * 16;

  // B fragment: B[k][o], k = kh*32 + quad*8 + j, o = nt*16+n
  short8 bfr[2][4];
#pragma unroll
  for (int nt = 0; nt < 4; ++nt)
#pragma unroll
    for (int kh = 0; kh < 2; ++kh)
      bfr[kh][nt] = *reinterpret_cast<const short8*>(
          w1abf + (nt * 16 + n) * 64 + kh * 32 + quad * 8);

  // A fragment: A[m=lane&15][k=quad*8+j]
  const int arow = min(ibase + n, NITEMS - 1);
  short8 afr[2];
#pragma unroll
  for (int kh = 0; kh < 2; ++kh) {
    const float4* p = reinterpret_cast<const float4*>(
        v2e + (size_t)arow * 64 + kh * 32 + quad * 8);
    const float4 x0 = p[0], x1 = p[1];
    short8 a;
    a[0] = f2bf(x0.x); a[1] = f2bf(x0.y); a[2] = f2bf(x0.z); a[3] = f2bf(x0.w);
    a[4] = f2bf(x1.x); a[5] = f2bf(x1.y); a[6] = f2bf(x1.z); a[7] = f2bf(x1.w);
    afr[kh] = a;
  }

  f32x4 d[4];
#pragma unroll
  for (int nt = 0; nt < 4; ++nt) {
    f32x4 z = {0.f, 0.f, 0.f, 0.f};
    z = __builtin_amdgcn_mfma_f32_16x16x32_bf16(afr[0], bfr[0][nt], z, 0, 0, 0);
    z = __builtin_amdgcn_mfma_f32_16x16x32_bf16(afr[1], bfr[1][nt], z, 0, 0, 0);
    d[nt] = z;
  }

  // C/D layout: col = n (o = nt*16+n), row m = quad*4 + reg  -> LDS transpose
#pragma unroll
  for (int nt = 0; nt < 4; ++nt)
#pragma unroll
    for (int r = 0; r < 4; ++r)
      sD[wave][quad * 4 + r][nt * 16 + n] = f2bf(d[nt][r]);

  __syncthreads();

  const int srow = lane >> 2, chunk = lane & 3;
  const short8 v0 = *reinterpret_cast<const short8*>(&sD[wave][srow][chunk * 16]);
  const short8 v1 = *reinterpret_cast<const short8*>(&sD[wave][srow][chunk * 16 + 8]);
  const int item = ibase + srow;
  if (item < NITEMS) {
    short* dst = pre_uv + (size_t)item * 64 + chunk * 16;
    *reinterpret_cast<short8*>(dst) = v0;
    *reinterpret_cast<short8*>(dst + 8) = v1;
  }
}

// ---------------------------------------------------------------------------
// k_main: one block per b. All 8 pre_uv gathers prefetched per wave before
// compute; pre_r5 served from LDS. h = relu(pre_uv[uv]+pre_r5[r]) -> bf16,
// layer 2 via MFMA, relu+bias, mean over l.
// ---------------------------------------------------------------------------
__global__ __launch_bounds__(256) void k_main(
    const short* __restrict__ pre_uv, const float* __restrict__ pre_r5,
    const short* __restrict__ w2bf, const float* __restrict__ w2b,
    const int* __restrict__ huv, const int* __restrict__ hrr,
    float* __restrict__ out)
{
  __shared__ __align__(16) float s_r5[5 * 68];   // stride 68: rows start on distinct banks
  __shared__ float red[4][64];

  const int tid  = threadIdx.x;
  const int wave = tid >> 6, lane = tid & 63;
  const int n = lane & 15, quad = lane >> 4;
  const int b = blockIdx.x;

  for (int idx = tid; idx < 5 * 64; idx += 256)
    s_r5[(idx >> 6) * 68 + (idx & 63)] = pre_r5[idx];

  // indices for this wave's 4 l-tiles (tile t: lbase = wave*16 + t*64; >=L masked)
  const int* hu = huv + b * LL;
  const int* hr = hrr + b * LL;
  int iv[4], ir[4];
#pragma unroll
  for (int t = 0; t < 4; ++t) {
    const int lc = min(wave * 16 + t * 64 + n, LL - 1);
    iv[t] = hu[lc];
    ir[t] = hr[lc];
  }

  // B fragments for W2^T: B[k][o] = w2[o][k]
  short8 bfr[2][4];
#pragma unroll
  for (int nt = 0; nt < 4; ++nt)
#pragma unroll
    for (int kh = 0; kh < 2; ++kh)
      bfr[kh][nt] = *reinterpret_cast<const short8*>(
          w2bf + (nt * 16 + n) * 64 + kh * 32 + quad * 8);

  float bias[4];
#pragma unroll
  for (int nt = 0; nt < 4; ++nt) bias[nt] = w2b[nt * 16 + n];

  // prefetch ALL pre_uv gathers (8 independent 16B loads in flight)
  short8 u[4][2];
#pragma unroll
  for (int t = 0; t < 4; ++t)
#pragma unroll
    for (int kh = 0; kh < 2; ++kh)
      u[t][kh] = *reinterpret_cast<const short8*>(
          pre_uv + (size_t)iv[t] * 64 + kh * 32 + quad * 8);

  __syncthreads();  // s_r5 ready

  float acc[4] = {0.f, 0.f, 0.f, 0.f};
#pragma unroll
  for (int t = 0; t < 4; ++t) {
    short8 afr[2];
#pragma unroll
    for (int kh = 0; kh < 2; ++kh) {
      const float4* rp = reinterpret_cast<const float4*>(
          s_r5 + ir[t] * 68 + kh * 32 + quad * 8);
      const float4 r0 = rp[0], r1 = rp[1];
      const float rv[8] = {r0.x, r0.y, r0.z, r0.w, r1.x, r1.y, r1.z, r1.w};
      short8 a;
#pragma unroll
      for (int j = 0; j < 8; ++j) {
        const float h = bf2f(u[t][kh][j]) + rv[j];
        a[j] = f2bf(fmaxf(h, 0.f));
      }
      afr[kh] = a;
    }

    f32x4 d[4];
#pragma unroll
    for (int nt = 0; nt < 4; ++nt) {
      f32x4 z = {0.f, 0.f, 0.f, 0.f};
      z = __builtin_amdgcn_mfma_f32_16x16x32_bf16(afr[0], bfr[0][nt], z, 0, 0, 0);
      z = __builtin_amdgcn_mfma_f32_16x16x32_bf16(afr[1], bfr[1][nt], z, 0, 0, 0);
      d[nt] = z;
    }

    const int lbase = wave * 16 + t * 64;
#pragma unroll
    for (int nt = 0; nt < 4; ++nt)
#pragma unroll
      for (int r = 0; r < 4; ++r) {
        const int rl = lbase + quad * 4 + r;
        const float v = fmaxf(d[nt][r] + bias[nt], 0.f);
        acc[nt] += (rl < LL) ? v : 0.f;
      }
  }

  // sum across the 4 quads (rows split across quads)
#pragma unroll
  for (int nt = 0; nt < 4; ++nt) {
    float v = acc[nt];
    v += __shfl_xor(v, 16, 64);
    v += __shfl_xor(v, 32, 64);
    acc[nt] = v;
  }

  if (lane < 16) {
#pragma unroll
    for (int nt = 0; nt < 4; ++nt) red[wave][nt * 16 + lane] = acc[nt];
  }
  __syncthreads();
  if (tid < 64) {
    const float s = red[0][tid] + red[1][tid] + red[2][tid] + red[3][tid];
    out[b * 64 + tid] = s * (1.0f / (float)LL);
  }
}

// ---------------------------------------------------------------------------
// Fallback (no workspace): all-fp32, one block per b, weights in padded LDS.
// ---------------------------------------------------------------------------
__global__ __launch_bounds__(256) void k_fallback(
    const float* __restrict__ v2e, const float* __restrict__ r2e,
    const float* __restrict__ w1W, const float* __restrict__ w1b,
    const float* __restrict__ w2W, const float* __restrict__ w2b,
    const int* __restrict__ huv, const int* __restrict__ hrr,
    float* __restrict__ out)
{
  __shared__ float sw1[64][129];
  __shared__ float sw2[64][65];
  __shared__ float sx[4][128];
  __shared__ float sh[4][64];
  __shared__ float red[4][64];

  const int tid = threadIdx.x;
  const int wave = tid >> 6, lane = tid & 63;
  const int b = blockIdx.x;

  for (int idx = tid; idx < 64 * 128; idx += 256) sw1[idx >> 7][idx & 127] = w1W[idx];
  for (int idx = tid; idx < 64 * 64; idx += 256) sw2[idx >> 6][idx & 63] = w2W[idx];
  __syncthreads();

  const float b1o = w1b[lane], b2o = w2b[lane];
  float acc = 0.f;

  for (int l = wave; l < LL; l += 4) {
    const int iv = huv[b * LL + l];
    const int ir = hrr[b * LL + l];
    sx[wave][lane]      = v2e[iv * 64 + lane];
    sx[wave][64 + lane] = r2e[ir * 64 + lane];
    __syncthreads();
    float h = b1o;
    for (int i = 0; i < 128; ++i) h += sx[wave][i] * sw1[lane][i];
    sh[wave][lane] = fmaxf(h, 0.f);
    __syncthreads();
    float o = b2o;
    for (int i = 0; i < 64; ++i) o += sh[wave][i] * sw2[lane][i];
    acc += fmaxf(o, 0.f);
  }

  red[wave][lane] = acc;
  __syncthreads();
  if (tid < 64) {
    const float s = red[0][tid] + red[1][tid] + red[2][tid] + red[3][tid];
    out[b * 64 + tid] = s * (1.0f / (float)LL);
  }
}

extern "C" void kernel_launch(void* const* d_in, const int* in_sizes, int n_in,
                              void* d_out, int out_size, void* d_ws, size_t ws_size,
                              hipStream_t stream) {
  (void)in_sizes; (void)n_in; (void)out_size;
  const float* v2e = (const float*)d_in[0];   // [100000,64]
  const float* r2e = (const float*)d_in[1];   // [5,64]
  const float* w1W = (const float*)d_in[2];   // [64,128]
  const float* w1b = (const float*)d_in[3];   // [64]
  const float* w2W = (const float*)d_in[4];   // [64,64]
  const float* w2b = (const float*)d_in[5];   // [64]
  // d_in[6] = nodes (unused by uv=True branch)
  const int* huv = (const int*)d_in[7];       // [4096,200]
  const int* hrr = (const int*)d_in[8];       // [4096,200]
  float* out = (float*)d_out;                 // [4096,64]

  const size_t OFF_R5  = (size_t)NITEMS * 64 * sizeof(short);   // 12,800,000
  const size_t OFF_W2  = OFF_R5 + NRATE * 64 * sizeof(float);   // +1,280
  const size_t OFF_W1A = OFF_W2 + 64 * 64 * sizeof(short);      // +8,192
  const size_t NEED    = OFF_W1A + 64 * 64 * sizeof(short);     // +8,192

  if (ws_size >= NEED) {
    short* pre_uv = (short*)d_ws;
    float* pre_r5 = (float*)((char*)d_ws + OFF_R5);
    short* w2bf   = (short*)((char*)d_ws + OFF_W2);
    short* w1abf  = (short*)((char*)d_ws + OFF_W1A);

    k_prep<<<13, 256, 0, stream>>>(r2e, w1W, w1b, w2W, w1abf, w2bf, pre_r5);
    k_pre_uv<<<(NITEMS + 63) / 64, 256, 0, stream>>>(v2e, w1abf, pre_uv);
    k_main<<<BB, 256, 0, stream>>>(pre_uv, pre_r5, w2bf, w2b, huv, hrr, out);
  } else {
    k_fallback<<<BB, 256, 0, stream>>>(v2e, r2e, w1W, w1b, w2W, w2b, huv, hrr, out);
  }
}

// Round 3
// 124.992 us; speedup vs baseline: 1.2293x; 1.0282x over previous
//
#include <hip/hip_runtime.h>

// Problem constants (from reference)
#define NITEMS 100000
#define NRATE  5
#define BB     4096
#define LL     200
#define DD     64
#define NBUV   391   // pre_uv blocks (391*256 = 100096 >= NITEMS)

typedef short short8  __attribute__((ext_vector_type(8)));
typedef short short4v __attribute__((ext_vector_type(4)));
typedef float f32x4   __attribute__((ext_vector_type(4)));

static __device__ __forceinline__ short f2bf(float f) {
  // round-to-nearest-even fp32 -> bf16 (finite inputs only)
  unsigned u = __builtin_bit_cast(unsigned, f);
  u += 0x7fffu + ((u >> 16) & 1u);
  return (short)(u >> 16);
}
static __device__ __forceinline__ float bf2f(short s) {
  return __builtin_bit_cast(float, (unsigned)((unsigned short)s) << 16);
}
// k-space permutation: storage position p holds h-component pi(p).
// pi(p) = (p&3)*16 + (p>>2). Applied consistently to pre_uv, pre_r5, w2 rows,
// so all MFMA dot products are unchanged (dot is permutation-invariant).
static __device__ __forceinline__ int kperm(int p) {
  return ((p & 3) << 4) | (p >> 2);
}

// ---------------------------------------------------------------------------
// k_pre: blocks 0..390: pre_uv[item][p] = bf16( (v2e[item] . w1a_row[pi(p)]) )
//        block 391    : w2p[o*64+p] = bf16(w2W[o][pi(p)]);
//                       r5p[r*64+p] = w1b[pi(p)] + r2e[r] . w1b_row[pi(p)]
// pre_uv via MFMA 16x16x32_bf16; the C-layout (lane n holds cols nt*16+n)
// stores transpose-free as short4 at offset n*4 thanks to kperm.
// ---------------------------------------------------------------------------
__global__ __launch_bounds__(256) void k_pre(
    const float* __restrict__ v2e, const float* __restrict__ r2e,
    const float* __restrict__ w1W, const float* __restrict__ w1b,
    const float* __restrict__ w2W,
    short* __restrict__ pre_uv, short* __restrict__ w2p,
    float* __restrict__ r5p)
{
  const int tid = threadIdx.x;
  const int blk = blockIdx.x;

  if (blk >= NBUV) {
    // ---- prep tail block ----
    for (int idx = tid; idx < 64 * 64; idx += 256) {
      const int o = idx >> 6, p = idx & 63;
      w2p[idx] = f2bf(w2W[o * 64 + kperm(p)]);
    }
    for (int idx = tid; idx < NRATE * 64; idx += 256) {
      const int r = idx >> 6, p = idx & 63;
      const int o = kperm(p);
      const float4* wr = reinterpret_cast<const float4*>(w1W + o * 128 + 64);
      const float4* rr = reinterpret_cast<const float4*>(r2e + r * 64);
      float s = w1b[o];
#pragma unroll
      for (int q = 0; q < 16; ++q) {
        const float4 a = wr[q], b = rr[q];
        s += a.x * b.x + a.y * b.y + a.z * b.z + a.w * b.w;
      }
      r5p[r * 64 + p] = s;
    }
    return;
  }

  // ---- pre_uv: 256 items/block, 64 per wave (4 iterations of 16) ----
  const int wave = tid >> 6, lane = tid & 63;
  const int n = lane & 15, quad = lane >> 4;

  // B fragment from fp32 w1W (item half, k<64), converted once per block:
  // B[k][o], k = kh*32 + quad*8 + j, o = nt*16 + n
  short8 bfr[2][4];
#pragma unroll
  for (int nt = 0; nt < 4; ++nt)
#pragma unroll
    for (int kh = 0; kh < 2; ++kh) {
      const float4* p = reinterpret_cast<const float4*>(
          w1W + (nt * 16 + n) * 128 + kh * 32 + quad * 8);
      const float4 x0 = p[0], x1 = p[1];
      short8 f;
      f[0] = f2bf(x0.x); f[1] = f2bf(x0.y); f[2] = f2bf(x0.z); f[3] = f2bf(x0.w);
      f[4] = f2bf(x1.x); f[5] = f2bf(x1.y); f[6] = f2bf(x1.z); f[7] = f2bf(x1.w);
      bfr[kh][nt] = f;
    }

  const int ibase_w = blk * 256 + wave * 64;

  // software-pipelined A loads: A[m=n][k=kh*32+quad*8+j]
  float4 cur0, cur1, cur2, cur3;
  {
    const int row = min(ibase_w + n, NITEMS - 1);
    const float4* p = reinterpret_cast<const float4*>(v2e + (size_t)row * 64 + quad * 8);
    cur0 = p[0]; cur1 = p[1];
    const float4* q = reinterpret_cast<const float4*>(v2e + (size_t)row * 64 + 32 + quad * 8);
    cur2 = q[0]; cur3 = q[1];
  }

#pragma unroll
  for (int it = 0; it < 4; ++it) {
    float4 nx0, nx1, nx2, nx3;
    if (it < 3) {
      const int row = min(ibase_w + (it + 1) * 16 + n, NITEMS - 1);
      const float4* p = reinterpret_cast<const float4*>(v2e + (size_t)row * 64 + quad * 8);
      nx0 = p[0]; nx1 = p[1];
      const float4* q = reinterpret_cast<const float4*>(v2e + (size_t)row * 64 + 32 + quad * 8);
      nx2 = q[0]; nx3 = q[1];
    }

    short8 afr[2];
    {
      short8 a;
      a[0] = f2bf(cur0.x); a[1] = f2bf(cur0.y); a[2] = f2bf(cur0.z); a[3] = f2bf(cur0.w);
      a[4] = f2bf(cur1.x); a[5] = f2bf(cur1.y); a[6] = f2bf(cur1.z); a[7] = f2bf(cur1.w);
      afr[0] = a;
      a[0] = f2bf(cur2.x); a[1] = f2bf(cur2.y); a[2] = f2bf(cur2.z); a[3] = f2bf(cur2.w);
      a[4] = f2bf(cur3.x); a[5] = f2bf(cur3.y); a[6] = f2bf(cur3.z); a[7] = f2bf(cur3.w);
      afr[1] = a;
    }

    f32x4 d[4];
#pragma unroll
    for (int nt = 0; nt < 4; ++nt) {
      f32x4 z = {0.f, 0.f, 0.f, 0.f};
      z = __builtin_amdgcn_mfma_f32_16x16x32_bf16(afr[0], bfr[0][nt], z, 0, 0, 0);
      z = __builtin_amdgcn_mfma_f32_16x16x32_bf16(afr[1], bfr[1][nt], z, 0, 0, 0);
      d[nt] = z;
    }

    // C/D: lane (n,quad), reg (nt,r) holds row quad*4+r, col nt*16+n.
    // Store cols {nt*16+n} at positions n*4+nt (kperm) -> contiguous short4.
#pragma unroll
    for (int r = 0; r < 4; ++r) {
      const int item = ibase_w + it * 16 + quad * 4 + r;
      if (item < NITEMS) {
        short4v s = {f2bf(d[0][r]), f2bf(d[1][r]), f2bf(d[2][r]), f2bf(d[3][r])};
        *reinterpret_cast<short4v*>(pre_uv + (size_t)item * 64 + n * 4) = s;
      }
    }

    if (it < 3) { cur0 = nx0; cur1 = nx1; cur2 = nx2; cur3 = nx3; }
  }
}

// ---------------------------------------------------------------------------
// k_main: one block per b. Wave w handles l-tiles lbase = w*16 + t*64 for
// t < ntiles (wave 0: 4 tiles, waves 1-3: 3 tiles -> 13 tiles cover L=200,
// dead tiles skipped wave-uniformly). All gathers issued before compute.
// pre_uv/r5p/w2p are all in permuted k-space -> contiguous 16B frag loads.
// ---------------------------------------------------------------------------
__global__ __launch_bounds__(256) void k_main(
    const short* __restrict__ pre_uv, const float* __restrict__ r5p,
    const short* __restrict__ w2p, const float* __restrict__ w2b,
    const int* __restrict__ huv, const int* __restrict__ hrr,
    float* __restrict__ out)
{
  __shared__ __align__(16) float s_r5[5 * 68];   // stride 68 spreads row starts
  __shared__ float red[4][64];

  const int tid  = threadIdx.x;
  const int wave = tid >> 6, lane = tid & 63;
  const int n = lane & 15, quad = lane >> 4;
  const int b = blockIdx.x;
  const int ntiles = (wave == 0) ? 4 : 3;

  for (int idx = tid; idx < 5 * 64; idx += 256)
    s_r5[(idx >> 6) * 68 + (idx & 63)] = r5p[idx];

  const int* hu = huv + b * LL;
  const int* hr = hrr + b * LL;
  int iv[4] = {0, 0, 0, 0}, ir[4] = {0, 0, 0, 0};
#pragma unroll
  for (int t = 0; t < 4; ++t)
    if (t < ntiles) {
      const int lc = min(wave * 16 + t * 64 + n, LL - 1);
      iv[t] = hu[lc];
      ir[t] = hr[lc];
    }

  // B fragments for W2 (permuted k-space): B[p][o] = w2p[o*64+p]
  short8 bfr[2][4];
#pragma unroll
  for (int nt = 0; nt < 4; ++nt)
#pragma unroll
    for (int kh = 0; kh < 2; ++kh)
      bfr[kh][nt] = *reinterpret_cast<const short8*>(
          w2p + (nt * 16 + n) * 64 + kh * 32 + quad * 8);

  float bias[4];
#pragma unroll
  for (int nt = 0; nt < 4; ++nt) bias[nt] = w2b[nt * 16 + n];

  // prefetch ALL pre_uv gathers (up to 8 independent 16B loads in flight)
  short8 u[4][2];
#pragma unroll
  for (int t = 0; t < 4; ++t)
    if (t < ntiles)
#pragma unroll
      for (int kh = 0; kh < 2; ++kh)
        u[t][kh] = *reinterpret_cast<const short8*>(
            pre_uv + (size_t)iv[t] * 64 + kh * 32 + quad * 8);

  __syncthreads();  // s_r5 ready

  float acc[4] = {0.f, 0.f, 0.f, 0.f};
#pragma unroll
  for (int t = 0; t < 4; ++t) {
    if (t >= ntiles) continue;   // wave-uniform skip of dead tiles
    short8 afr[2];
#pragma unroll
    for (int kh = 0; kh < 2; ++kh) {
      const float4* rp = reinterpret_cast<const float4*>(
          s_r5 + ir[t] * 68 + kh * 32 + quad * 8);
      const float4 r0 = rp[0], r1 = rp[1];
      const float rv[8] = {r0.x, r0.y, r0.z, r0.w, r1.x, r1.y, r1.z, r1.w};
      short8 a;
#pragma unroll
      for (int j = 0; j < 8; ++j) {
        const float h = bf2f(u[t][kh][j]) + rv[j];
        a[j] = f2bf(fmaxf(h, 0.f));
      }
      afr[kh] = a;
    }

    f32x4 d[4];
#pragma unroll
    for (int nt = 0; nt < 4; ++nt) {
      f32x4 z = {0.f, 0.f, 0.f, 0.f};
      z = __builtin_amdgcn_mfma_f32_16x16x32_bf16(afr[0], bfr[0][nt], z, 0, 0, 0);
      z = __builtin_amdgcn_mfma_f32_16x16x32_bf16(afr[1], bfr[1][nt], z, 0, 0, 0);
      d[nt] = z;
    }

    const int lbase = wave * 16 + t * 64;
#pragma unroll
    for (int nt = 0; nt < 4; ++nt)
#pragma unroll
      for (int r = 0; r < 4; ++r) {
        const int rl = lbase + quad * 4 + r;
        const float v = fmaxf(d[nt][r] + bias[nt], 0.f);
        acc[nt] += (rl < LL) ? v : 0.f;
      }
  }

  // sum across the 4 quads (C rows split across quads)
#pragma unroll
  for (int nt = 0; nt < 4; ++nt) {
    float v = acc[nt];
    v += __shfl_xor(v, 16, 64);
    v += __shfl_xor(v, 32, 64);
    acc[nt] = v;
  }

  if (lane < 16) {
#pragma unroll
    for (int nt = 0; nt < 4; ++nt) red[wave][nt * 16 + lane] = acc[nt];
  }
  __syncthreads();
  if (tid < 64) {
    const float s = red[0][tid] + red[1][tid] + red[2][tid] + red[3][tid];
    out[b * 64 + tid] = s * (1.0f / (float)LL);
  }
}

// ---------------------------------------------------------------------------
// Fallback (no workspace): all-fp32, one block per b, weights in padded LDS.
// ---------------------------------------------------------------------------
__global__ __launch_bounds__(256) void k_fallback(
    const float* __restrict__ v2e, const float* __restrict__ r2e,
    const float* __restrict__ w1W, const float* __restrict__ w1b,
    const float* __restrict__ w2W, const float* __restrict__ w2b,
    const int* __restrict__ huv, const int* __restrict__ hrr,
    float* __restrict__ out)
{
  __shared__ float sw1[64][129];
  __shared__ float sw2[64][65];
  __shared__ float sx[4][128];
  __shared__ float sh[4][64];
  __shared__ float red[4][64];

  const int tid = threadIdx.x;
  const int wave = tid >> 6, lane = tid & 63;
  const int b = blockIdx.x;

  for (int idx = tid; idx < 64 * 128; idx += 256) sw1[idx >> 7][idx & 127] = w1W[idx];
  for (int idx = tid; idx < 64 * 64; idx += 256) sw2[idx >> 6][idx & 63] = w2W[idx];
  __syncthreads();

  const float b1o = w1b[lane], b2o = w2b[lane];
  float acc = 0.f;

  for (int l = wave; l < LL; l += 4) {
    const int iv = huv[b * LL + l];
    const int ir = hrr[b * LL + l];
    sx[wave][lane]      = v2e[iv * 64 + lane];
    sx[wave][64 + lane] = r2e[ir * 64 + lane];
    __syncthreads();
    float h = b1o;
    for (int i = 0; i < 128; ++i) h += sx[wave][i] * sw1[lane][i];
    sh[wave][lane] = fmaxf(h, 0.f);
    __syncthreads();
    float o = b2o;
    for (int i = 0; i < 64; ++i) o += sh[wave][i] * sw2[lane][i];
    acc += fmaxf(o, 0.f);
  }

  red[wave][lane] = acc;
  __syncthreads();
  if (tid < 64) {
    const float s = red[0][tid] + red[1][tid] + red[2][tid] + red[3][tid];
    out[b * 64 + tid] = s * (1.0f / (float)LL);
  }
}

extern "C" void kernel_launch(void* const* d_in, const int* in_sizes, int n_in,
                              void* d_out, int out_size, void* d_ws, size_t ws_size,
                              hipStream_t stream) {
  (void)in_sizes; (void)n_in; (void)out_size;
  const float* v2e = (const float*)d_in[0];   // [100000,64]
  const float* r2e = (const float*)d_in[1];   // [5,64]
  const float* w1W = (const float*)d_in[2];   // [64,128]
  const float* w1b = (const float*)d_in[3];   // [64]
  const float* w2W = (const float*)d_in[4];   // [64,64]
  const float* w2b = (const float*)d_in[5];   // [64]
  // d_in[6] = nodes (unused by uv=True branch)
  const int* huv = (const int*)d_in[7];       // [4096,200]
  const int* hrr = (const int*)d_in[8];       // [4096,200]
  float* out = (float*)d_out;                 // [4096,64]

  const size_t OFF_R5 = (size_t)NITEMS * 64 * sizeof(short);   // 12,800,000
  const size_t OFF_W2 = OFF_R5 + NRATE * 64 * sizeof(float);   // +1,280
  const size_t NEED   = OFF_W2 + 64 * 64 * sizeof(short);      // +8,192

  if (ws_size >= NEED) {
    short* pre_uv = (short*)d_ws;
    float* r5p    = (float*)((char*)d_ws + OFF_R5);
    short* w2p    = (short*)((char*)d_ws + OFF_W2);

    k_pre<<<NBUV + 1, 256, 0, stream>>>(v2e, r2e, w1W, w1b, w2W, pre_uv, w2p, r5p);
    k_main<<<BB, 256, 0, stream>>>(pre_uv, r5p, w2p, w2b, huv, hrr, out);
  } else {
    k_fallback<<<BB, 256, 0, stream>>>(v2e, r2e, w1W, w1b, w2W, w2b, huv, hrr, out);
  }
}